// Round 1
// baseline (202.793 us; speedup 1.0000x reference)
//
#include <hip/hip_runtime.h>
#include <hip/hip_bf16.h>
#include <math.h>

#define NROWS 131072   // B*T = 32*4096
#define KC    512      // codebook size
#define DD    64       // embedding dim
#define NELEM (NROWS * DD)

#define OUT_IDX_OFF  NELEM
#define OUT_LOSS_OFF (NELEM + NROWS)

#define MARGIN 3e-5f

// d_ws byte offsets
#define WSO_CNT   0                        // int   flagged-row count
#define WSO_DONE  4                        // int   refine blocks-done count
#define WSO_LOSS  8                        // float loss accumulator
#define WSO_WNORM 64                       // float wnorm_np[512]
#define WSO_BH    4096                     // bf16 frags W-hi: 32 tiles x 2 kh x 64 lanes x 8 = 64 KB
#define WSO_BL    (WSO_BH + 65536)         // bf16 frags W-lo: 64 KB
#define WSO_LIST  (WSO_BL + 65536)         // int flagList[NROWS]

typedef __attribute__((ext_vector_type(8))) short short8;
typedef __attribute__((ext_vector_type(4))) float f32x4;

// ---------------------------------------------------------------------------
// bf16 helpers (RNE via __float2bfloat16)
// ---------------------------------------------------------------------------
__device__ __forceinline__ short f2bf_bits(float f) {
  __hip_bfloat16 h = __float2bfloat16(f);
  short s; __builtin_memcpy(&s, &h, 2); return s;
}
__device__ __forceinline__ float bfbits2f(short s) {
  __hip_bfloat16 h; __builtin_memcpy(&h, &s, 2);
  return __bfloat162float(h);
}
// split 8 consecutive f32 into bf16 hi + bf16 lo(residual)
__device__ __forceinline__ void cvt8(const float* __restrict__ p, short8& hi, short8& lo) {
#pragma unroll
  for (int j = 0; j < 8; j++) {
    float f = p[j];
    short hb = f2bf_bits(f);
    float r = f - bfbits2f(hb);
    hi[j] = hb;
    lo[j] = f2bf_bits(r);
  }
}

// ---------------------------------------------------------------------------
// numpy's pairwise sum of squares for 64 contiguous f32 (8-accumulator tree).
// contract(off) REQUIRED (hipcc default -ffp-contract=fast would fuse).
// ---------------------------------------------------------------------------
__device__ __forceinline__ float np_sumsq64(const float* __restrict__ p) {
#pragma clang fp contract(off)
  float r0 = p[0] * p[0], r1 = p[1] * p[1], r2 = p[2] * p[2], r3 = p[3] * p[3];
  float r4 = p[4] * p[4], r5 = p[5] * p[5], r6 = p[6] * p[6], r7 = p[7] * p[7];
  for (int i = 8; i < 64; i += 8) {
    r0 = r0 + p[i + 0] * p[i + 0];
    r1 = r1 + p[i + 1] * p[i + 1];
    r2 = r2 + p[i + 2] * p[i + 2];
    r3 = r3 + p[i + 3] * p[i + 3];
    r4 = r4 + p[i + 4] * p[i + 4];
    r5 = r5 + p[i + 5] * p[i + 5];
    r6 = r6 + p[i + 6] * p[i + 6];
    r7 = r7 + p[i + 7] * p[i + 7];
  }
  return ((r0 + r1) + (r2 + r3)) + ((r4 + r5) + (r6 + r7));
}

// ---------------------------------------------------------------------------
// Kernel 0: prep. (a) W -> MFMA-B-fragment-major bf16 hi/lo arrays.
// B[k=d][n=cw] fragment for 16x16x32: lane L holds B[(L>>4)*8+j][L&15], j=0..7.
// Element (tile t, khalf h, lane L, j) = W[cw = t*16+(L&15)][d = 32h+(L>>4)*8+j].
// (b) wnorm_np[k] = numpy-exact sum(W[k]^2).
// (c) zero the ws scalars (absorbs the old hipMemsetAsync -> one fewer op).
// ---------------------------------------------------------------------------
__global__ void k_prep(const float* __restrict__ W, short8* __restrict__ Bh,
                       short8* __restrict__ Bl, float* __restrict__ wnorm,
                       int* __restrict__ flagCnt, int* __restrict__ doneCnt,
                       float* __restrict__ lossSum) {
  int gtid = blockIdx.x * blockDim.x + threadIdx.x;  // 0..4095
  if (gtid == 0) { *flagCnt = 0; *doneCnt = 0; *lossSum = 0.0f; }
  int t = gtid >> 7, rem = gtid & 127;
  int h = rem >> 6, L = rem & 63;
  int cw = (t << 4) + (L & 15);
  int dbase = (h << 5) + ((L >> 4) << 3);
  short8 hi, lo;
  cvt8(W + (cw << 6) + dbase, hi, lo);
  Bh[gtid] = hi;  // gtid == ((t*2+h)*64 + L)
  Bl[gtid] = lo;
  if (gtid < KC) wnorm[gtid] = np_sumsq64(W + (gtid << 6));
}

// ---------------------------------------------------------------------------
// Kernel 1: fused MFMA screen + argmin + epilogue.
// OCCUPANCY REWORK vs previous version: 32 rows/wave (MT=2) instead of 64,
// grid 1024 blocks -> 16 waves/CU (was 8; grid-limited, VGPR=84 allowed more).
// __launch_bounds__(256,4) keeps VGPR <= 128 so 4 waves/SIMD actually fit.
// B fragments are software-prefetched one tile ahead (L2-hot stream).
// score_k = wnorm_np[k] - 2*(zh.wh + zl.wh + zh.wl)  [drops row-const ||z||^2;
// error <= ~3e-6 abs, covered by MARGIN]. Per-lane best/second/idx over its
// col slice (ascending k -> strict < keeps first index), xor-butterfly merge
// over the 16 col-lanes with index tie-break.
// EPILOGUE REWORK: after the butterfly, (b1,b2,bi) is identical across all 16
// lanes of a quad group -> no shfl broadcasts needed. Each quad group handles
// its own 8 rows with float4 accesses (4 groups in parallel, 8 iters vs 64).
// ---------------------------------------------------------------------------
#define MT 2                 // M-tiles per wave
#define ROWS_PER_WAVE (MT * 16)
#define ROWS_PER_BLOCK (ROWS_PER_WAVE * 4)

__global__ __launch_bounds__(256, 4) void k_screen(
    const float* __restrict__ z, const float* __restrict__ W,
    const short8* __restrict__ Bh, const short8* __restrict__ Bl,
    const float* __restrict__ wnorm, float* __restrict__ out,
    int* __restrict__ flagList, int* __restrict__ flagCnt,
    float* __restrict__ lossSum) {
  const int lane = threadIdx.x & 63;
  const int wave = threadIdx.x >> 6;
  const int rowBase = blockIdx.x * ROWS_PER_BLOCK + wave * ROWS_PER_WAVE;
  const int m = lane & 15, quad = lane >> 4;

  // ---- A fragments: zh/zl for MT M-tiles x 2 k-halves ----
  short8 Ah[MT][2], Al[MT][2];
#pragma unroll
  for (int mt = 0; mt < MT; mt++) {
    const float* zp = z + (size_t)(rowBase + (mt << 4) + m) * DD + (quad << 3);
#pragma unroll
    for (int h = 0; h < 2; h++) cvt8(zp + (h << 5), Ah[mt][h], Al[mt][h]);
  }

  float b1[MT][4], b2[MT][4];
  int bi[MT][4];
#pragma unroll
  for (int mt = 0; mt < MT; mt++)
#pragma unroll
    for (int r = 0; r < 4; r++) { b1[mt][r] = 1e30f; b2[mt][r] = 1e30f; bi[mt][r] = 0; }

  // ---- main loop over 32 codeword tiles, one-tile B prefetch ----
  short8 cBh[2], cBl[2];
#pragma unroll
  for (int h = 0; h < 2; h++) {
    cBh[h] = Bh[(h << 6) + lane];
    cBl[h] = Bl[(h << 6) + lane];
  }
  float cwn = wnorm[m];

  for (int t = 0; t < 32; t++) {
    const int tn = (t + 1) & 31;  // wrap: last iter reloads tile 0 (harmless)
    short8 nBh[2], nBl[2];
#pragma unroll
    for (int h = 0; h < 2; h++) {
      nBh[h] = Bh[(((tn << 1) + h) << 6) + lane];
      nBl[h] = Bl[(((tn << 1) + h) << 6) + lane];
    }
    float nwn = wnorm[(tn << 4) + m];

    f32x4 acc[MT] = {{0.f, 0.f, 0.f, 0.f}, {0.f, 0.f, 0.f, 0.f}};
#pragma unroll
    for (int h = 0; h < 2; h++) {
#pragma unroll
      for (int mt = 0; mt < MT; mt++)
        acc[mt] = __builtin_amdgcn_mfma_f32_16x16x32_bf16(Ah[mt][h], cBh[h], acc[mt], 0, 0, 0);
#pragma unroll
      for (int mt = 0; mt < MT; mt++)
        acc[mt] = __builtin_amdgcn_mfma_f32_16x16x32_bf16(Al[mt][h], cBh[h], acc[mt], 0, 0, 0);
#pragma unroll
      for (int mt = 0; mt < MT; mt++)
        acc[mt] = __builtin_amdgcn_mfma_f32_16x16x32_bf16(Ah[mt][h], cBl[h], acc[mt], 0, 0, 0);
    }

    int colv = (t << 4) + m;
#pragma unroll
    for (int mt = 0; mt < MT; mt++)
#pragma unroll
      for (int r = 0; r < 4; r++) {
        float s = fmaf(-2.0f, acc[mt][r], cwn);
        if (s < b1[mt][r]) { b2[mt][r] = b1[mt][r]; b1[mt][r] = s; bi[mt][r] = colv; }
        else b2[mt][r] = fminf(b2[mt][r], s);
      }

    cBh[0] = nBh[0]; cBh[1] = nBh[1];
    cBl[0] = nBl[0]; cBl[1] = nBl[1];
    cwn = nwn;
  }

  // ---- merge across the 16 col-lanes (xor butterfly within quad group).
  // Symmetric compare: after 4 steps all 16 lanes of a quad group hold the
  // identical merged (b1,b2,bi).
#pragma unroll
  for (int off = 1; off < 16; off <<= 1) {
#pragma unroll
    for (int mt = 0; mt < MT; mt++)
#pragma unroll
      for (int r = 0; r < 4; r++) {
        float o1 = __shfl_xor(b1[mt][r], off, 64);
        float o2 = __shfl_xor(b2[mt][r], off, 64);
        int oi = __shfl_xor(bi[mt][r], off, 64);
        if (o1 < b1[mt][r] || (o1 == b1[mt][r] && oi < bi[mt][r])) {
          b2[mt][r] = fminf(b1[mt][r], o2);
          b1[mt][r] = o1; bi[mt][r] = oi;
        } else {
          b2[mt][r] = fminf(b2[mt][r], o1);
        }
      }
  }

  // ---- epilogue: quad-group-parallel, shfl-free.
  // Quad group q owns rows mt*16 + q*4 + r; its 16 lanes cover the 64 cols
  // as float4 (16 lanes x 16 B = one row). (b1,b2,bi) already uniform in-group.
  float lossAcc = 0.f;
#pragma unroll
  for (int mt = 0; mt < MT; mt++)
#pragma unroll
    for (int r = 0; r < 4; r++) {
      const int row = rowBase + (mt << 4) + (quad << 2) + r;
      const int ki = bi[mt][r];
      f32x4 zv = *(const f32x4*)(z + (size_t)row * DD + (m << 2));
      f32x4 wv = *(const f32x4*)(W + (ki << 6) + (m << 2));
      f32x4 ov;
#pragma unroll
      for (int j = 0; j < 4; j++) {
        float tt = wv[j] - zv[j];
        ov[j] = zv[j] + tt;  // matches reference z + (z_q - z)
        float dl = zv[j] - ov[j];
        lossAcc = fmaf(dl, dl, lossAcc);
      }
      *(f32x4*)(out + (size_t)row * DD + (m << 2)) = ov;
      if (m == 0) {
        out[OUT_IDX_OFF + row] = (float)ki;
        if (b2[mt][r] - b1[mt][r] < MARGIN) {
          int slot = atomicAdd(flagCnt, 1);
          flagList[slot] = row;
        }
      }
    }

#pragma unroll
  for (int off = 1; off < 64; off <<= 1) lossAcc += __shfl_xor(lossAcc, off, 64);
  if (lane == 0) atomicAdd(lossSum, lossAcc);
}

// ---------------------------------------------------------------------------
// Kernel 2: numpy-f32 replication for flagged rows + patch out/loss.
// dist_np = fl32( fl32(A + wnp[k]) - fl32(2*C) ), C = f64 dot rounded once.
// Tail: last-block-done pattern finalizes the loss (absorbs old k_finalize).
// ---------------------------------------------------------------------------
__global__ void k_refine(const float* __restrict__ z, const float* __restrict__ W,
                         const float* __restrict__ wnp, float* __restrict__ out,
                         const int* __restrict__ flagList,
                         const int* __restrict__ flagCnt,
                         float* __restrict__ lossSum, int* __restrict__ doneCnt) {
  int nflag = *flagCnt;
  int lane = threadIdx.x & 63;
  int wave = (blockIdx.x * blockDim.x + threadIdx.x) >> 6;
  int nWaves = (gridDim.x * blockDim.x) >> 6;

  for (int f = wave; f < nflag; f += nWaves) {
    int row = flagList[f];
    const float* zr = z + (size_t)row * DD;
    float A = np_sumsq64(zr);

    float best = 1e30f;
    int bk = 0x7fffffff;
#pragma unroll
    for (int j = 0; j < KC / 64; j++) {
      int k = lane + (j << 6);
      const float* wk = W + (k << 6);
      double cd = 0.0;
      for (int d = 0; d < DD; d++) cd = fma((double)zr[d], (double)wk[d], cd);
      float twoC = (float)(2.0 * cd);
      float dist;
      {
#pragma clang fp contract(off)
        float t1 = A + wnp[k];
        dist = t1 - twoC;
      }
      if (dist < best || (dist == best && k < bk)) { best = dist; bk = k; }
    }
#pragma unroll
    for (int off = 1; off < 64; off <<= 1) {
      float ov = __shfl_xor(best, off, 64);
      int ok = __shfl_xor(bk, off, 64);
      if (ov < best || (ov == best && ok < bk)) { best = ov; bk = ok; }
    }

    int kold = (int)out[OUT_IDX_OFF + row];
    if (bk != kold) {
      float zv = zr[lane];
      float wN = W[(bk << 6) + lane];
      float oOld = out[(size_t)row * DD + lane];
      float tN = wN - zv;
      float oN = zv + tN;
      out[(size_t)row * DD + lane] = oN;
      float dN = zv - oN, dO = zv - oOld;
      float delta = dN * dN - dO * dO;
#pragma unroll
      for (int off = 1; off < 64; off <<= 1) delta += __shfl_xor(delta, off, 64);
      if (lane == 0) {
        atomicAdd(lossSum, delta);
        out[OUT_IDX_OFF + row] = (float)bk;
      }
    }
  }

  // ---- finalize: last block to arrive writes the loss scalar ----
  __syncthreads();
  if (threadIdx.x == 0) {
    __threadfence();
    int d = atomicAdd(doneCnt, 1);
    if (d == (int)gridDim.x - 1) {
      float s = atomicAdd(lossSum, 0.0f);  // atomic read sees all prior adds
      out[OUT_LOSS_OFF] = 0.25f * s / (float)NELEM;
    }
  }
}

extern "C" void kernel_launch(void* const* d_in, const int* in_sizes, int n_in,
                              void* d_out, int out_size, void* d_ws, size_t ws_size,
                              hipStream_t stream) {
  const float* z = (const float*)d_in[0];
  const float* W = (const float*)d_in[1];
  float* out = (float*)d_out;
  char* ws = (char*)d_ws;

  int* flagCnt = (int*)(ws + WSO_CNT);
  int* doneCnt = (int*)(ws + WSO_DONE);
  float* lossSum = (float*)(ws + WSO_LOSS);
  float* wnorm = (float*)(ws + WSO_WNORM);
  short8* Bh = (short8*)(ws + WSO_BH);
  short8* Bl = (short8*)(ws + WSO_BL);
  int* flagList = (int*)(ws + WSO_LIST);

  k_prep<<<16, 256, 0, stream>>>(W, Bh, Bl, wnorm, flagCnt, doneCnt, lossSum);
  k_screen<<<NROWS / ROWS_PER_BLOCK, 256, 0, stream>>>(z, W, Bh, Bl, wnorm, out,
                                                       flagList, flagCnt, lossSum);
  k_refine<<<256, 256, 0, stream>>>(z, W, wnorm, out, flagList, flagCnt,
                                    lossSum, doneCnt);
}